// Round 9
// baseline (245.255 us; speedup 1.0000x reference)
//
#include <hip/hip_runtime.h>

// Problem constants (from reference)
#define N_NODES 20000
#define BATCH   4
#define DIN     32
#define DOUT    64
#define MSTEPS  7            // M = MAX_STEP*S + 1
#define ROW     128          // DIN*BATCH, channels per node
#define NROW    896          // ROW*MSTEPS bf16 per node (split: 2 halves of 448)
#define NHALFU  224          // uints per node per half (7 slices x 32)
#define PLN     656          // LDS plane stride (shorts): 16 rows * 40 + 16 pad
#define NT      79           // 256-node dst tiles per support (79*256 >= 20000)
#define KB2     (2 * NT)     // coarse buckets = 158
#define CHUNK   2048         // P2 edges per block
#define SLOT    12288        // staged slot per bucket (mean 8192, +45 sigma)
#define WSLOT   3584         // csr slot per 64-node window (pad16 worst-case 3144)
#define SGRID   (N_NODES / 2)   // spmm blocks per unit: 4 nodes x 2 halves per 2 blocks
#define PGRID   625             // ceil(2E / CHUNK) for E=640000
#define TGRID   1250            // N*16 threads / 256 (vectorized transpose)

typedef short  short8 __attribute__((ext_vector_type(8)));
typedef float  f32x4  __attribute__((ext_vector_type(4)));

__device__ __forceinline__ unsigned short f2bf(float f) {
    unsigned u = __float_as_uint(f);
    unsigned r = u + 0x7fff + ((u >> 16) & 1);   // RNE to bf16
    return (unsigned short)(r >> 16);
}
__device__ __forceinline__ float bf_lo(unsigned p) { return __uint_as_float(p << 16); }
__device__ __forceinline__ float bf_hi(unsigned p) { return __uint_as_float(p & 0xffff0000u); }

// init: block 0 seeds slot cursors; blocks 1..56 pre-pack W into bf16 fragment
// order Wbf[m*2048 + o*32 + c] = bf16(W[o*224 + c*7 + m])  (c = quad*8+j).
__global__ void init_k(int* __restrict__ cursor, const float* __restrict__ W,
                       unsigned short* __restrict__ Wbf) {
    if (blockIdx.x == 0) {
        if (threadIdx.x < KB2) cursor[threadIdx.x] = threadIdx.x * SLOT;
        return;
    }
    int i = (int)(blockIdx.x - 1) * 256 + threadIdx.x;   // 56*256 = 14336 = 7*64*32
    int m = i >> 11;
    int o = (i >> 5) & 63;
    int c = i & 31;
    Wbf[i] = f2bf(W[o * 224 + c * 7 + m]);
}

// ---- Fused P2-partition + input-transpose (disjoint block ranges overlap) ----
// blocks [0,PGRID): LDS-staged partition of edges into coarse (s, dst>>8)
//   bucket slots; staged entry {src|bf16val<<16, dst}.
// blocks [PGRID, PGRID+TGRID): vectorized transpose into the m=0 slice of the
//   CHANNEL-SPLIT layout: uint addr = h*N*224 + n*224 + m*32 + cu, where
//   channel c -> uint u = c/2, h = u>>5, cu = u&31  (h == b>>1).
__global__ void __launch_bounds__(256) p2t_k(const int* __restrict__ src,
                                             const int* __restrict__ dst,
                                             const float* __restrict__ vals,
                                             int* __restrict__ cursor,
                                             uint2* __restrict__ staged,
                                             const float* __restrict__ in,
                                             unsigned* __restrict__ xu, int E) {
    __shared__ int lhist[KB2];
    __shared__ int lbase[KB2];
    __shared__ int gbase[KB2];
    __shared__ int sc[256];
    __shared__ uint2 buf[CHUNK];
    __shared__ unsigned short kk[CHUNK];
    int t = threadIdx.x;
    if (blockIdx.x >= PGRID) {
        // transpose branch: N*16 threads total
        int tid = (blockIdx.x - PGRID) * 256 + t;
        if (tid < N_NODES * 16) {
            int dq = tid & 3;             // d-octet
            int b  = (tid >> 2) & 3;
            int n  = tid >> 4;
            int d0 = dq * 8;
            const float* ip = in + ((size_t)b * N_NODES + n) * DIN + d0;
            float4 f0 = *(const float4*)ip;
            float4 f1 = *(const float4*)(ip + 4);
            uint4 o;
            o.x = (unsigned)f2bf(f0.x) | ((unsigned)f2bf(f0.y) << 16);
            o.y = (unsigned)f2bf(f0.z) | ((unsigned)f2bf(f0.w) << 16);
            o.z = (unsigned)f2bf(f1.x) | ((unsigned)f2bf(f1.y) << 16);
            o.w = (unsigned)f2bf(f1.z) | ((unsigned)f2bf(f1.w) << 16);
            size_t off = (size_t)(b >> 1) * N_NODES * NHALFU + (size_t)n * NHALFU
                       + (b & 1) * 16 + dq * 4;      // slice m=0
            *(uint4*)(xu + off) = o;
        }
        return;
    }
    int base = blockIdx.x * CHUNK;
    int nval = min(CHUNK, 2 * E - base);
    for (int i = t; i < KB2; i += 256) lhist[i] = 0;
    __syncthreads();
    int k[CHUNK / 256], pos[CHUNK / 256];
    uint2 pay[CHUNK / 256];
#pragma unroll
    for (int j = 0; j < CHUNK / 256; ++j) {
        int i = j * 256 + t;
        int e = base + i;
        if (i < nval) {
            int s = (e >= E) ? 1 : 0;
            int d = dst[e];
            pay[j] = make_uint2((unsigned)src[e] | ((unsigned)f2bf(vals[e]) << 16),
                                (unsigned)d);
            k[j] = s * NT + (d >> 8);
            pos[j] = atomicAdd(&lhist[k[j]], 1);
        } else k[j] = -1;
    }
    __syncthreads();
    int v = (t < KB2) ? lhist[t] : 0;
    sc[t] = v;
    __syncthreads();
    for (int off = 1; off < 256; off <<= 1) {
        int a = (t >= off) ? sc[t - off] : 0;
        __syncthreads();
        sc[t] += a;
        __syncthreads();
    }
    if (t < KB2) lbase[t] = sc[t] - v;
    __syncthreads();
    if (t < KB2 && lhist[t]) gbase[t] = atomicAdd(&cursor[t], lhist[t]);
#pragma unroll
    for (int j = 0; j < CHUNK / 256; ++j) {
        if (k[j] >= 0) {
            int slot = lbase[k[j]] + pos[j];
            buf[slot] = pay[j];
            kk[slot] = (unsigned short)k[j];
        }
    }
    __syncthreads();
#pragma unroll
    for (int j = 0; j < CHUNK / 256; ++j) {
        int i = j * 256 + t;
        if (i < nval) {
            int b = kk[i];
            staged[gbase[b] + (i - lbase[b])] = buf[i];
        }
    }
}

// P3: one block per 64-node window (4 windows per bucket, grid 4*KB2).
// Rows padded to x16 with {src=0,val=0}; writes row_desc {start, padded_cnt}.
__global__ void __launch_bounds__(256) p3_fine_k(const uint2* __restrict__ staged,
                                                 const int* __restrict__ cursor,
                                                 int2* __restrict__ row_desc,
                                                 unsigned* __restrict__ csr) {
    __shared__ int lhist[64];
    __shared__ int sc[64];
    __shared__ int lcur[64];
    int bb = blockIdx.x;
    int b = bb >> 2, sub = bb & 3;
    int s = b / NT, tile = b - s * NT;
    int w0loc = sub * 64;                    // window start within tile
    int seg0 = b * SLOT;
    int len = cursor[b] - seg0;
    int t = threadIdx.x;
    if (t < 64) lhist[t] = 0;
    __syncthreads();
    for (int i = t; i < len; i += 256) {
        int dl = (int)(staged[seg0 + i].y & 255) - w0loc;
        if (dl >= 0 && dl < 64) atomicAdd(&lhist[dl], 1);
    }
    __syncthreads();
    int cntr = (t < 64) ? lhist[t] : 0;
    int pl = (cntr + 15) & ~15;              // pad to x16 for the pipelined gather core
    if (t < 64) sc[t] = pl;
    __syncthreads();
    for (int off = 1; off < 64; off <<= 1) {
        int a = (t < 64 && t >= off) ? sc[t - off] : 0;
        __syncthreads();
        if (t < 64) sc[t] += a;
        __syncthreads();
    }
    int wbase = bb * WSLOT;
    if (t < 64) {
        int excl = sc[t] - pl;
        lcur[t] = wbase + excl;
        int nd = tile * 256 + w0loc + t;
        if (nd < N_NODES) row_desc[s * N_NODES + nd] = make_int2(wbase + excl, pl);
    }
    __syncthreads();
    for (int i = t; i < len; i += 256) {
        uint2 u = staged[seg0 + i];
        int dl = (int)(u.y & 255) - w0loc;
        if (dl >= 0 && dl < 64) {
            int p = atomicAdd(&lcur[dl], 1);
            csr[p] = u.x;
        }
    }
    if (t < 64) {
        int excl = sc[t] - pl;
        for (int i = cntr; i < pl; ++i) csr[wbase + excl + i] = 0u;
    }
}

// ---- Channel-split SpMM gather core ----
// Wave = one node-HALF (128B). col = lane&31 (uint within half), eo = lane>>5
// (edge subset). Each gather instruction serves 2 edges x 2 lines. csr loads
// stay wave-uniform. Two-deep pipeline over 16-edge chunks (rows are x16).
// half = blockIdx.x & 1 => with round-robin block->XCD dispatch each XCD
// touches only one 2.56MB half-slice, which fits its 4MB L2.
__device__ __forceinline__ void issue2x8(const unsigned* __restrict__ csr, int e,
                                         const unsigned* __restrict__ xb,
                                         int col, int eo,
                                         unsigned cc[8], unsigned p[8]) {
    uint4 q0 = *(const uint4*)(csr + e);
    uint4 q1 = *(const uint4*)(csr + e + 4);
    uint4 q2 = *(const uint4*)(csr + e + 8);
    uint4 q3 = *(const uint4*)(csr + e + 12);
    cc[0] = eo ? q2.x : q0.x;
    cc[1] = eo ? q2.y : q0.y;
    cc[2] = eo ? q2.z : q0.z;
    cc[3] = eo ? q2.w : q0.w;
    cc[4] = eo ? q3.x : q1.x;
    cc[5] = eo ? q3.y : q1.y;
    cc[6] = eo ? q3.z : q1.z;
    cc[7] = eo ? q3.w : q1.w;
#pragma unroll
    for (int j = 0; j < 8; ++j)
        p[j] = xb[(size_t)(cc[j] & 0xffffu) * NHALFU + col];
}

__device__ __forceinline__ void fmac8(const unsigned c[8], const unsigned p[8],
                                      float acc[8]) {
#pragma unroll
    for (int j = 0; j < 8; ++j) {
        float v = bf_hi(c[j]);
        acc[j & 3]       = fmaf(v, bf_lo(p[j]), acc[j & 3]);
        acc[4 + (j & 3)] = fmaf(v, bf_hi(p[j]), acc[4 + (j & 3)]);
    }
}

// xb/xprevb/yb are HALF-SLICE bases: xu + h*N*224 + m*32; node stride 224.
__device__ __forceinline__ void spmm_core_h(const int2* __restrict__ rdesc,
                                            const unsigned* __restrict__ csr,
                                            const unsigned* __restrict__ xb,
                                            const unsigned* __restrict__ xprevb,
                                            unsigned* __restrict__ yb,
                                            float alpha, int node, int lane) {
    int col = lane & 31, eo = lane >> 5;
    int2 rd = rdesc[node];
    int start = rd.x, len = rd.y;
    float acc[8];
#pragma unroll
    for (int j = 0; j < 8; ++j) acc[j] = 0.f;
    if (len) {
        unsigned cA[8], pA[8], cB[8], pB[8];
        int n16 = len >> 4;
        issue2x8(csr, start, xb, col, eo, cA, pA);
        int k = 1;
        for (; k + 1 < n16; k += 2) {
            issue2x8(csr, start + k * 16, xb, col, eo, cB, pB);
            fmac8(cA, pA, acc);
            issue2x8(csr, start + (k + 1) * 16, xb, col, eo, cA, pA);
            fmac8(cB, pB, acc);
        }
        if (k < n16) {
            issue2x8(csr, start + k * 16, xb, col, eo, cB, pB);
            fmac8(cA, pA, acc);
            fmac8(cB, pB, acc);
        } else {
            fmac8(cA, pA, acc);
        }
    }
    float s0 = (acc[0] + acc[1]) + (acc[2] + acc[3]);
    float s1 = (acc[4] + acc[5]) + (acc[6] + acc[7]);
    s0 += __shfl_xor(s0, 32);          // fold the two edge subsets
    s1 += __shfl_xor(s1, 32);
    float r0 = alpha * s0, r1 = alpha * s1;
    if (xprevb) {
        unsigned pp = xprevb[(size_t)node * NHALFU + col];
        r0 -= bf_lo(pp);
        r1 -= bf_hi(pp);
    }
    if (eo == 0)
        yb[(size_t)node * NHALFU + col] =
            (unsigned)f2bf(r0) | ((unsigned)f2bf(r1) << 16);
}

// slice indices passed as ints; mprev < 0 means "no subtract".
__global__ void __launch_bounds__(256) spmm_row_k(const int2* __restrict__ rdesc,
                                                  const unsigned* __restrict__ csr,
                                                  unsigned* __restrict__ xu,
                                                  int msrc, int mprev, int mdst,
                                                  float alpha) {
    int bid = blockIdx.x;
    int half = bid & 1;
    int node = __builtin_amdgcn_readfirstlane((bid >> 1) * 4 + (threadIdx.x >> 6));
    int lane = threadIdx.x & 63;
    unsigned* hb = xu + (size_t)half * N_NODES * NHALFU;
    spmm_core_h(rdesc, csr, hb + msrc * 32,
                (mprev >= 0) ? hb + mprev * 32 : nullptr,
                hb + mdst * 32, alpha, node, lane);
}

// dual dispatch: blocks [0,SGRID) A-stream (X3 = 2 A0 X2 - X1),
// [SGRID,2*SGRID) B-stream (X4 = A1 X2), same input slice m=2.
__global__ void __launch_bounds__(256) spmm_dual_k(const int2* __restrict__ rdA,
                                                   const int2* __restrict__ rdB,
                                                   const unsigned* __restrict__ csr,
                                                   unsigned* __restrict__ xu) {
    int bid = blockIdx.x;
    int second = (bid >= SGRID) ? 1 : 0;
    int b2 = bid - second * SGRID;
    int half = b2 & 1;
    int node = __builtin_amdgcn_readfirstlane((b2 >> 1) * 4 + (threadIdx.x >> 6));
    int lane = threadIdx.x & 63;
    unsigned* hb = xu + (size_t)half * N_NODES * NHALFU;
    if (second)
        spmm_core_h(rdB, csr, hb + 2 * 32, nullptr, hb + 4 * 32, 1.0f, node, lane);
    else
        spmm_core_h(rdA, csr, hb + 2 * 32, hb + 1 * 32, hb + 3 * 32, 2.0f, node, lane);
}

// ---- MFMA epilogue (R6 LDS-staged structure; source re-indexed for the
// split layout — LDS planes and MFMA mapping unchanged/verified) ----
__global__ void __launch_bounds__(256) epilogue_mfma_k(const unsigned* __restrict__ xu,
                                                       const unsigned short* __restrict__ Wbf,
                                                       const float* __restrict__ bias,
                                                       float* __restrict__ out) {
    __shared__ unsigned short Alds[28 * PLN];   // 36736 B
    int tid = threadIdx.x;
    int lane = tid & 63, ot = tid >> 6;
    int col = lane & 15, quad = lane >> 4;
    int o = ot * 16 + col;

    short8 bfrag[MSTEPS];
#pragma unroll
    for (int m = 0; m < MSTEPS; ++m)
        bfrag[m] = *(const short8*)&Wbf[m * 2048 + o * 32 + quad * 8];
    float bo = bias[o];

    int n0 = blockIdx.x * 16;
#pragma unroll
    for (int it = 0; it < 7; ++it) {
        int idx = tid + it * 256;
        int r   = idx / 112;             // node row 0..15
        int rem = idx - r * 112;         // [m][b][dq]
        int m   = rem >> 4;
        int b   = (rem >> 2) & 3;
        int dq  = rem & 3;
        size_t off = (size_t)(b >> 1) * N_NODES * NHALFU
                   + (size_t)(n0 + r) * NHALFU + m * 32 + (b & 1) * 16 + dq * 4;
        uint4 q = *(const uint4*)(xu + off);
        *(uint4*)&Alds[(b * 7 + m) * PLN + r * 40 + dq * 8] = q;
    }
    __syncthreads();

    f32x4 acc[BATCH];
#pragma unroll
    for (int b = 0; b < BATCH; ++b)
        acc[b] = (f32x4){bo, bo, bo, bo};

#pragma unroll
    for (int m = 0; m < MSTEPS; ++m) {
#pragma unroll
        for (int b = 0; b < BATCH; ++b) {
            short8 a = *(const short8*)&Alds[(b * 7 + m) * PLN + col * 40 + quad * 8];
            acc[b] = __builtin_amdgcn_mfma_f32_16x16x32_bf16(a, bfrag[m], acc[b], 0, 0, 0);
        }
    }

#pragma unroll
    for (int b = 0; b < BATCH; ++b) {
#pragma unroll
        for (int reg = 0; reg < 4; ++reg) {
            int n = n0 + quad * 4 + reg;
            out[((size_t)b * N_NODES + n) * DOUT + o] = acc[b][reg];
        }
    }
}

extern "C" void kernel_launch(void* const* d_in, const int* in_sizes, int n_in,
                              void* d_out, int out_size, void* d_ws, size_t ws_size,
                              hipStream_t stream) {
    const float* inputs    = (const float*)d_in[0];
    const float* edge_vals = (const float*)d_in[1];
    const float* W         = (const float*)d_in[2];
    const float* bias      = (const float*)d_in[3];
    const int*   edge_src  = (const int*)d_in[4];
    const int*   edge_dst  = (const int*)d_in[5];
    float* out = (float*)d_out;
    const int E = in_sizes[1] / 2;   // edges per support

    unsigned* xu   = (unsigned*)d_ws;                              // 2 halves x N x 224 uints
    uint2* staged  = (uint2*)(xu + (size_t)2 * N_NODES * NHALFU);  // KB2*SLOT*8 = 15.5 MB
    unsigned* csr  = (unsigned*)(staged + (size_t)KB2 * SLOT);     // 4*KB2*WSLOT*4 = 9.1 MB
    int* cursor    = (int*)(csr + (size_t)4 * KB2 * WSLOT);        // KB2
    int2* row_desc = (int2*)(cursor + KB2 + 2);                    // 2*N int2
    unsigned short* Wbf = (unsigned short*)(row_desc + 2 * N_NODES); // 14336 bf16

    const int epgrid = N_NODES / 16;

    // ---- CSR build + transpose: init(+Wprep) -> fused(partition || transpose) -> fine ----
    init_k<<<57, 256, 0, stream>>>(cursor, W, Wbf);
    p2t_k<<<PGRID + TGRID, 256, 0, stream>>>(edge_src, edge_dst, edge_vals, cursor,
                                             staged, inputs, xu, E);
    p3_fine_k<<<4 * KB2, 256, 0, stream>>>(staged, cursor, row_desc, csr);

    const int2* rd0 = row_desc;
    const int2* rd1 = row_desc + N_NODES;

    // chain on split layout (slice index m passed to kernels):
    // X1 = A0 X0 ; X2 = 2 A0 X1 - X0 ; {X3 = 2 A0 X2 - X1 || X4 = A1 X2} ;
    // X5 = 2 A1 X4 - X2 ; X6 = 2 A1 X5 - X4
    spmm_row_k<<<SGRID, 256, 0, stream>>>(rd0, csr, xu, 0, -1, 1, 1.0f);
    spmm_row_k<<<SGRID, 256, 0, stream>>>(rd0, csr, xu, 1, 0, 2, 2.0f);
    spmm_dual_k<<<2 * SGRID, 256, 0, stream>>>(rd0, rd1, csr, xu);
    spmm_row_k<<<SGRID, 256, 0, stream>>>(rd1, csr, xu, 4, 2, 5, 2.0f);
    spmm_row_k<<<SGRID, 256, 0, stream>>>(rd1, csr, xu, 5, 4, 6, 2.0f);

    epilogue_mfma_k<<<epgrid, 256, 0, stream>>>(xu, Wbf, bias, out);
}

// Round 10
// 216.743 us; speedup vs baseline: 1.1315x; 1.1315x over previous
//
#include <hip/hip_runtime.h>

// Problem constants (from reference)
#define N_NODES 20000
#define BATCH   4
#define DIN     32
#define DOUT    64
#define MSTEPS  7            // M = MAX_STEP*S + 1
#define ROW     128          // DIN*BATCH, channels per node
#define NROW    896          // ROW*MSTEPS elements per node (all m packed), bf16
#define NROWU   448          // NROW in uints
#define PLN     656          // LDS plane stride (shorts): 16 rows * 40 + 16 pad
#define NT      79           // 256-node dst tiles per support (79*256 >= 20000)
#define KB2     (2 * NT)     // coarse buckets = 158
#define CHUNK   2048         // P2 edges per block
#define SLOT    12288        // staged slot per bucket (mean 8192, +45 sigma)
#define WSLOT   3584         // csr slot per 64-node window (pad16 worst-case 3144)
#define RGRID   (N_NODES / 4)   // spmm blocks per stream (4 nodes/block)
#define PGRID   625             // ceil(2E / CHUNK) for E=640000
#define TGRID   1250            // N*16 threads / 256 (vectorized transpose)

typedef short  short8 __attribute__((ext_vector_type(8)));
typedef float  f32x4  __attribute__((ext_vector_type(4)));

__device__ __forceinline__ unsigned short f2bf(float f) {
    unsigned u = __float_as_uint(f);
    unsigned r = u + 0x7fff + ((u >> 16) & 1);   // RNE to bf16
    return (unsigned short)(r >> 16);
}
__device__ __forceinline__ float bf_lo(unsigned p) { return __uint_as_float(p << 16); }
__device__ __forceinline__ float bf_hi(unsigned p) { return __uint_as_float(p & 0xffff0000u); }

// init: block 0 seeds slot cursors; blocks 1..56 pre-pack W into bf16 fragment
// order Wbf[m*2048 + o*32 + c] = bf16(W[o*224 + c*7 + m])  (c = quad*8+j).
__global__ void init_k(int* __restrict__ cursor, const float* __restrict__ W,
                       unsigned short* __restrict__ Wbf) {
    if (blockIdx.x == 0) {
        if (threadIdx.x < KB2) cursor[threadIdx.x] = threadIdx.x * SLOT;
        return;
    }
    int i = (int)(blockIdx.x - 1) * 256 + threadIdx.x;   // 56*256 = 14336 = 7*64*32
    int m = i >> 11;
    int o = (i >> 5) & 63;
    int c = i & 31;
    Wbf[i] = f2bf(W[o * 224 + c * 7 + m]);
}

// ---- Fused P2-partition + input-transpose (disjoint block ranges overlap) ----
// blocks [0,PGRID): LDS-staged partition of edges into coarse (s, dst>>8)
//   bucket slots; staged entry {src|bf16val<<16, dst}.
// blocks [PGRID, PGRID+TGRID): vectorized transpose into the m=0 slice with
//   row layout [m][b][d] (d fastest): xs[n*896 + b*32 + d] = bf16(in[b,n,d]).
__global__ void __launch_bounds__(256) p2t_k(const int* __restrict__ src,
                                             const int* __restrict__ dst,
                                             const float* __restrict__ vals,
                                             int* __restrict__ cursor,
                                             uint2* __restrict__ staged,
                                             const float* __restrict__ in,
                                             unsigned short* __restrict__ xs, int E) {
    __shared__ int lhist[KB2];
    __shared__ int lbase[KB2];
    __shared__ int gbase[KB2];
    __shared__ int sc[256];
    __shared__ uint2 buf[CHUNK];
    __shared__ unsigned short kk[CHUNK];
    int t = threadIdx.x;
    if (blockIdx.x >= PGRID) {
        // transpose branch: N*16 threads total
        int tid = (blockIdx.x - PGRID) * 256 + t;
        if (tid < N_NODES * 16) {
            int dq = tid & 3;             // d-octet
            int b  = (tid >> 2) & 3;
            int n  = tid >> 4;
            int d0 = dq * 8;
            const float* ip = in + ((size_t)b * N_NODES + n) * DIN + d0;
            float4 f0 = *(const float4*)ip;
            float4 f1 = *(const float4*)(ip + 4);
            uint4 o;
            o.x = (unsigned)f2bf(f0.x) | ((unsigned)f2bf(f0.y) << 16);
            o.y = (unsigned)f2bf(f0.z) | ((unsigned)f2bf(f0.w) << 16);
            o.z = (unsigned)f2bf(f1.x) | ((unsigned)f2bf(f1.y) << 16);
            o.w = (unsigned)f2bf(f1.z) | ((unsigned)f2bf(f1.w) << 16);
            *(uint4*)(xs + (size_t)n * NROW + b * 32 + d0) = o;
        }
        return;
    }
    int base = blockIdx.x * CHUNK;
    int nval = min(CHUNK, 2 * E - base);
    for (int i = t; i < KB2; i += 256) lhist[i] = 0;
    __syncthreads();
    int k[CHUNK / 256], pos[CHUNK / 256];
    uint2 pay[CHUNK / 256];
#pragma unroll
    for (int j = 0; j < CHUNK / 256; ++j) {
        int i = j * 256 + t;
        int e = base + i;
        if (i < nval) {
            int s = (e >= E) ? 1 : 0;
            int d = dst[e];
            pay[j] = make_uint2((unsigned)src[e] | ((unsigned)f2bf(vals[e]) << 16),
                                (unsigned)d);
            k[j] = s * NT + (d >> 8);
            pos[j] = atomicAdd(&lhist[k[j]], 1);
        } else k[j] = -1;
    }
    __syncthreads();
    int v = (t < KB2) ? lhist[t] : 0;
    sc[t] = v;
    __syncthreads();
    for (int off = 1; off < 256; off <<= 1) {
        int a = (t >= off) ? sc[t - off] : 0;
        __syncthreads();
        sc[t] += a;
        __syncthreads();
    }
    if (t < KB2) lbase[t] = sc[t] - v;
    __syncthreads();
    if (t < KB2 && lhist[t]) gbase[t] = atomicAdd(&cursor[t], lhist[t]);
#pragma unroll
    for (int j = 0; j < CHUNK / 256; ++j) {
        if (k[j] >= 0) {
            int slot = lbase[k[j]] + pos[j];
            buf[slot] = pay[j];
            kk[slot] = (unsigned short)k[j];
        }
    }
    __syncthreads();
#pragma unroll
    for (int j = 0; j < CHUNK / 256; ++j) {
        int i = j * 256 + t;
        if (i < nval) {
            int b = kk[i];
            staged[gbase[b] + (i - lbase[b])] = buf[i];
        }
    }
}

// P3: one block per 64-node window (4 windows per bucket, grid 4*KB2).
// Rows padded to x16 with {src=0,val=0}; writes row_desc {start, padded_cnt}.
__global__ void __launch_bounds__(256) p3_fine_k(const uint2* __restrict__ staged,
                                                 const int* __restrict__ cursor,
                                                 int2* __restrict__ row_desc,
                                                 unsigned* __restrict__ csr) {
    __shared__ int lhist[64];
    __shared__ int sc[64];
    __shared__ int lcur[64];
    int bb = blockIdx.x;
    int b = bb >> 2, sub = bb & 3;
    int s = b / NT, tile = b - s * NT;
    int w0loc = sub * 64;                    // window start within tile
    int seg0 = b * SLOT;
    int len = cursor[b] - seg0;
    int t = threadIdx.x;
    if (t < 64) lhist[t] = 0;
    __syncthreads();
    for (int i = t; i < len; i += 256) {
        int dl = (int)(staged[seg0 + i].y & 255) - w0loc;
        if (dl >= 0 && dl < 64) atomicAdd(&lhist[dl], 1);
    }
    __syncthreads();
    int cntr = (t < 64) ? lhist[t] : 0;
    int pl = (cntr + 15) & ~15;              // pad to x16 for the pipelined gather core
    if (t < 64) sc[t] = pl;
    __syncthreads();
    for (int off = 1; off < 64; off <<= 1) {
        int a = (t < 64 && t >= off) ? sc[t - off] : 0;
        __syncthreads();
        if (t < 64) sc[t] += a;
        __syncthreads();
    }
    int wbase = bb * WSLOT;
    if (t < 64) {
        int excl = sc[t] - pl;
        lcur[t] = wbase + excl;
        int nd = tile * 256 + w0loc + t;
        if (nd < N_NODES) row_desc[s * N_NODES + nd] = make_int2(wbase + excl, pl);
    }
    __syncthreads();
    for (int i = t; i < len; i += 256) {
        uint2 u = staged[seg0 + i];
        int dl = (int)(u.y & 255) - w0loc;
        if (dl >= 0 && dl < 64) {
            int p = atomicAdd(&lcur[dl], 1);
            csr[p] = u.x;
        }
    }
    if (t < 64) {
        int excl = sc[t] - pl;
        for (int i = cntr; i < pl; ++i) csr[wbase + excl + i] = 0u;
    }
}

// ---- SpMM gather core, 16-wide 2-deep software pipeline (R6-verified) ----
// Rows are multiples of 16 (pad {src=0,val=0}). Per 16-edge chunk: 4 uint4
// csr loads + 16 gathers issued as a batch; the pipeline overlaps chunk k+1's
// gathers with chunk k's FMAs.
__device__ __forceinline__ void issue16(const unsigned* __restrict__ csr, int e,
                                        const unsigned* __restrict__ xb, int lane,
                                        unsigned c[16], unsigned p[16]) {
    uint4 q0 = *(const uint4*)(csr + e);
    uint4 q1 = *(const uint4*)(csr + e + 4);
    uint4 q2 = *(const uint4*)(csr + e + 8);
    uint4 q3 = *(const uint4*)(csr + e + 12);
    c[0]=q0.x;  c[1]=q0.y;  c[2]=q0.z;  c[3]=q0.w;
    c[4]=q1.x;  c[5]=q1.y;  c[6]=q1.z;  c[7]=q1.w;
    c[8]=q2.x;  c[9]=q2.y;  c[10]=q2.z; c[11]=q2.w;
    c[12]=q3.x; c[13]=q3.y; c[14]=q3.z; c[15]=q3.w;
#pragma unroll
    for (int j = 0; j < 16; ++j)
        p[j] = xb[(size_t)(c[j] & 0xffffu) * NROWU + lane];
}

__device__ __forceinline__ void fmac16(const unsigned c[16], const unsigned p[16],
                                       float acc[8]) {
#pragma unroll
    for (int j = 0; j < 16; ++j) {
        float v = bf_hi(c[j]);
        acc[j & 3]       = fmaf(v, bf_lo(p[j]), acc[j & 3]);
        acc[4 + (j & 3)] = fmaf(v, bf_hi(p[j]), acc[4 + (j & 3)]);
    }
}

__device__ __forceinline__ void spmm_core(const int2* __restrict__ rdesc,
                                          const unsigned* __restrict__ csr,
                                          const unsigned* __restrict__ xb,
                                          const unsigned* __restrict__ xprevb,
                                          unsigned* __restrict__ yb,
                                          float alpha, int node, int lane) {
    int2 rd = rdesc[node];
    int start = rd.x, len = rd.y;
    float acc[8];
#pragma unroll
    for (int j = 0; j < 8; ++j) acc[j] = 0.f;
    if (len) {
        unsigned cA[16], pA[16], cB[16], pB[16];
        int n16 = len >> 4;
        issue16(csr, start, xb, lane, cA, pA);
        int k = 1;
        for (; k + 1 < n16; k += 2) {
            issue16(csr, start + k * 16, xb, lane, cB, pB);
            fmac16(cA, pA, acc);
            issue16(csr, start + (k + 1) * 16, xb, lane, cA, pA);
            fmac16(cB, pB, acc);
        }
        if (k < n16) {
            issue16(csr, start + k * 16, xb, lane, cB, pB);
            fmac16(cA, pA, acc);
            fmac16(cB, pB, acc);
        } else {
            fmac16(cA, pA, acc);
        }
    }
    float r0 = alpha * ((acc[0] + acc[1]) + (acc[2] + acc[3]));
    float r1 = alpha * ((acc[4] + acc[5]) + (acc[6] + acc[7]));
    if (xprevb) {
        unsigned pp = xprevb[(size_t)node * NROWU + lane];
        r0 -= bf_lo(pp);
        r1 -= bf_hi(pp);
    }
    yb[(size_t)node * NROWU + lane] = (unsigned)f2bf(r0) | ((unsigned)f2bf(r1) << 16);
}

__global__ void __launch_bounds__(256) spmm_row_k(const int2* __restrict__ rdesc,
                                                  const unsigned* __restrict__ csr,
                                                  const unsigned short* __restrict__ x,
                                                  const unsigned short* __restrict__ xprev,
                                                  unsigned short* __restrict__ y, float alpha) {
    int node = __builtin_amdgcn_readfirstlane(blockIdx.x * 4 + (threadIdx.x >> 6));
    int lane = threadIdx.x & 63;
    spmm_core(rdesc, csr, (const unsigned*)x, (const unsigned*)xprev, (unsigned*)y,
              alpha, node, lane);
}

// dual dispatch: blocks [0,RGRID) A-stream, [RGRID,2*RGRID) B-stream, same input x.
// x3 = 2*A0*x2 - x1 ; x4 = A1*x2.
__global__ void __launch_bounds__(256) spmm_dual_k(const int2* __restrict__ rdA,
                                                   const int2* __restrict__ rdB,
                                                   const unsigned* __restrict__ csr,
                                                   const unsigned short* __restrict__ x,
                                                   const unsigned short* __restrict__ xprevA,
                                                   unsigned short* __restrict__ yA,
                                                   unsigned short* __restrict__ yB) {
    int bid = blockIdx.x;
    int second = (bid >= RGRID) ? 1 : 0;
    int node = __builtin_amdgcn_readfirstlane((bid - second * RGRID) * 4 + (threadIdx.x >> 6));
    int lane = threadIdx.x & 63;
    const int2* rd = second ? rdB : rdA;
    const unsigned* xprevb = second ? nullptr : (const unsigned*)xprevA;
    unsigned* yb = second ? (unsigned*)yB : (unsigned*)yA;
    float alpha = second ? 1.0f : 2.0f;
    spmm_core(rd, csr, (const unsigned*)x, xprevb, yb, alpha, node, lane);
}

// ---- MFMA epilogue (R6 LDS-staged structure; bfrag from pre-packed Wbf) ----
// Row layout [m][b][d]: LDS stage is one ds_write_b128 per uint4.
__global__ void __launch_bounds__(256) epilogue_mfma_k(const unsigned short* __restrict__ xs,
                                                       const unsigned short* __restrict__ Wbf,
                                                       const float* __restrict__ bias,
                                                       float* __restrict__ out) {
    __shared__ unsigned short Alds[28 * PLN];   // 36736 B
    int tid = threadIdx.x;
    int lane = tid & 63, ot = tid >> 6;
    int col = lane & 15, quad = lane >> 4;
    int o = ot * 16 + col;

    short8 bfrag[MSTEPS];
#pragma unroll
    for (int m = 0; m < MSTEPS; ++m)
        bfrag[m] = *(const short8*)&Wbf[m * 2048 + o * 32 + quad * 8];
    float bo = bias[o];

    int n0 = blockIdx.x * 16;
    const uint4* src = (const uint4*)(xs + (size_t)n0 * NROW);   // 1792 uint4
#pragma unroll
    for (int it = 0; it < 7; ++it) {
        int idx = tid + it * 256;
        uint4 q = src[idx];
        int r   = idx / 112;             // node row 0..15
        int rem = idx - r * 112;         // uint4 within row: [m][b][dq]
        int m   = rem >> 4;
        int b   = (rem >> 2) & 3;
        int d0  = (rem & 3) * 8;
        *(uint4*)&Alds[(b * 7 + m) * PLN + r * 40 + d0] = q;
    }
    __syncthreads();

    f32x4 acc[BATCH];
#pragma unroll
    for (int b = 0; b < BATCH; ++b)
        acc[b] = (f32x4){bo, bo, bo, bo};

#pragma unroll
    for (int m = 0; m < MSTEPS; ++m) {
#pragma unroll
        for (int b = 0; b < BATCH; ++b) {
            short8 a = *(const short8*)&Alds[(b * 7 + m) * PLN + col * 40 + quad * 8];
            acc[b] = __builtin_amdgcn_mfma_f32_16x16x32_bf16(a, bfrag[m], acc[b], 0, 0, 0);
        }
    }

#pragma unroll
    for (int b = 0; b < BATCH; ++b) {
#pragma unroll
        for (int reg = 0; reg < 4; ++reg) {
            int n = n0 + quad * 4 + reg;
            out[((size_t)b * N_NODES + n) * DOUT + o] = acc[b][reg];
        }
    }
}

extern "C" void kernel_launch(void* const* d_in, const int* in_sizes, int n_in,
                              void* d_out, int out_size, void* d_ws, size_t ws_size,
                              hipStream_t stream) {
    const float* inputs    = (const float*)d_in[0];
    const float* edge_vals = (const float*)d_in[1];
    const float* W         = (const float*)d_in[2];
    const float* bias      = (const float*)d_in[3];
    const int*   edge_src  = (const int*)d_in[4];
    const int*   edge_dst  = (const int*)d_in[5];
    float* out = (float*)d_out;
    const int E = in_sizes[1] / 2;   // edges per support

    unsigned short* xs = (unsigned short*)d_ws;                    // 35.84 MB
    uint2* staged  = (uint2*)(xs + (size_t)N_NODES * NROW);        // KB2*SLOT*8 = 15.5 MB
    unsigned* csr  = (unsigned*)(staged + (size_t)KB2 * SLOT);     // 4*KB2*WSLOT*4 = 9.1 MB
    int* cursor    = (int*)(csr + (size_t)4 * KB2 * WSLOT);        // KB2
    int2* row_desc = (int2*)(cursor + KB2 + 2);                    // 2*N int2
    unsigned short* Wbf = (unsigned short*)(row_desc + 2 * N_NODES); // 14336 bf16

    const int epgrid = N_NODES / 16;

    // ---- CSR build + transpose: init(+Wprep) -> fused(partition || transpose) -> fine ----
    init_k<<<57, 256, 0, stream>>>(cursor, W, Wbf);
    p2t_k<<<PGRID + TGRID, 256, 0, stream>>>(edge_src, edge_dst, edge_vals, cursor,
                                             staged, inputs, xs, E);
    p3_fine_k<<<4 * KB2, 256, 0, stream>>>(staged, cursor, row_desc, csr);

    const int2* rd0 = row_desc;
    const int2* rd1 = row_desc + N_NODES;

    // xs_m slice base = xs + m*128 (node stride NROW elements)
    unsigned short* X0 = xs + 0 * ROW;
    unsigned short* X1 = xs + 1 * ROW;
    unsigned short* X2 = xs + 2 * ROW;
    unsigned short* X3 = xs + 3 * ROW;
    unsigned short* X4 = xs + 4 * ROW;
    unsigned short* X5 = xs + 5 * ROW;
    unsigned short* X6 = xs + 6 * ROW;

    // support 0: xs1 = A0 x0 ; xs2 = 2 A0 xs1 - xs0
    spmm_row_k<<<RGRID, 256, 0, stream>>>(rd0, csr, X0, nullptr, X1, 1.0f);
    spmm_row_k<<<RGRID, 256, 0, stream>>>(rd0, csr, X1, X0,      X2, 2.0f);
    // xs3 = 2 A0 xs2 - xs1  ||  xs4 = A1 xs2   (independent; merged dispatch)
    spmm_dual_k<<<2 * RGRID, 256, 0, stream>>>(rd0, rd1, csr, X2, X1, X3, X4);
    // support 1 tail: xs5 = 2 A1 xs4 - xs2 ; xs6 = 2 A1 xs5 - xs4
    spmm_row_k<<<RGRID, 256, 0, stream>>>(rd1, csr, X4, X2, X5, 2.0f);
    spmm_row_k<<<RGRID, 256, 0, stream>>>(rd1, csr, X5, X4, X6, 2.0f);

    epilogue_mfma_k<<<epgrid, 256, 0, stream>>>(xs, Wbf, bias, out);
}